// Round 1
// baseline (155.332 us; speedup 1.0000x reference)
//
#include <hip/hip_runtime.h>

// ConvAttention collapse:
//   softmax_j(Aq[i]+Ak[j]+ba) == softmax_j(Ak_linear[j])   (i-terms & biases cancel)
//   out[i] = Wv * (sum_j sm[j] * x[j]) + bv                (identical for all i)
// Only x, Wk, Wv, bv, Wa[:,C:] are used.

#define HW    9216      // 96*96
#define HDIM  96
#define WDIM  96
#define CDIM  128
#define LDIM  16

// ---------------- K1: effective conv weight -----------------------------
// weff[c'][tap] = sum_c Wk[c][c'] * Wa[(128+c)][tap]   (tap = kh*5+kw)
__global__ void k_weff(const float* __restrict__ Wk, const float* __restrict__ Wa,
                       float* __restrict__ weff) {
    int idx = blockIdx.x * 256 + threadIdx.x;
    if (idx >= 128 * 25) return;
    int cp = idx / 25, tap = idx % 25;
    float s = 0.f;
    for (int c = 0; c < 128; ++c)
        s += Wk[c * 128 + cp] * Wa[(128 + c) * 25 + tap];
    weff[idx] = s;
}

// ---------------- K2: fused 5x5 conv of x with weff ----------------------
// grid (16 imgs, 3 rowtiles of 32, 8 channel-groups of 16), block 192.
// Each block accumulates its 16 channels' contribution into part[g][j][:].
__global__ __launch_bounds__(192) void k_conv(const float* __restrict__ x,
                                              const float* __restrict__ weff,
                                              float* __restrict__ part) {
    const int j  = blockIdx.x;
    const int rt = blockIdx.y;
    const int g  = blockIdx.z;
    const int c0 = g * 16;
    __shared__ float tile[36 * 104];   // rows rowbase-2..+33, cols -4..99
    __shared__ float wsm[16 * 25];
    const int tid = threadIdx.x;
    for (int i = tid; i < 16 * 25; i += 192) wsm[i] = weff[c0 * 25 + i];
    const int cq = tid % 24;           // float4-column 0..23 (cols 4cq..4cq+3)
    const int rg = tid / 24;           // 0..7
    const int r0 = rg * 4;             // 4 output rows per thread
    const int rowbase = rt * 32;

    float4 acc[4];
    acc[0] = acc[1] = acc[2] = acc[3] = make_float4(0.f, 0.f, 0.f, 0.f);

    for (int ch = 0; ch < 16; ++ch) {
        const float* xc = x + (size_t)(j * CDIM + c0 + ch) * HW;
        __syncthreads();               // protect previous iter's tile reads
        for (int idx = tid; idx < 36 * 26; idx += 192) {
            int r = idx / 26, q = idx % 26;
            int gr = rowbase - 2 + r;
            int gc = q * 4 - 4;
            float4 v = make_float4(0.f, 0.f, 0.f, 0.f);
            if (gr >= 0 && gr < HDIM && gc >= 0 && gc < WDIM)
                v = *(const float4*)(xc + gr * WDIM + gc);
            *(float4*)(tile + r * 104 + q * 4) = v;
        }
        __syncthreads();
        const float* wc = wsm + ch * 25;
        for (int rr = 0; rr < 8; ++rr) {          // window tile rows r0..r0+7
            const float* trow = tile + (r0 + rr) * 104 + cq * 4;
            float4 a  = *(const float4*)(trow);
            float4 b  = *(const float4*)(trow + 4);
            float4 c4 = *(const float4*)(trow + 8);
            float win[12] = {a.x, a.y, a.z, a.w, b.x, b.y, b.z, b.w,
                             c4.x, c4.y, c4.z, c4.w};
            // win[i] is global col 4cq-4+i; output col 4cq+o needs i=o+kw+2
            #pragma unroll
            for (int orow = 0; orow < 4; ++orow) {
                int kh = rr - orow;
                if (kh < 0 || kh > 4) continue;   // wave-uniform branch
                #pragma unroll
                for (int kw = 0; kw < 5; ++kw) {
                    float w = wc[kh * 5 + kw];
                    acc[orow].x += w * win[kw + 2];
                    acc[orow].y += w * win[kw + 3];
                    acc[orow].z += w * win[kw + 4];
                    acc[orow].w += w * win[kw + 5];
                }
            }
        }
    }
    float* pr = part + (size_t)(g * 16 + j) * HW;
    #pragma unroll
    for (int orow = 0; orow < 4; ++orow) {
        int row = rowbase + r0 + orow;
        *(float4*)(pr + row * WDIM + cq * 4) = acc[orow];
    }
}

// ---------------- K3: combine partials + softmax over j ------------------
__global__ void k_softmax(const float* __restrict__ part, float* __restrict__ sm) {
    int px = blockIdx.x * 256 + threadIdx.x;   // 9216 total
    float s[16];
    #pragma unroll
    for (int jj = 0; jj < 16; ++jj) s[jj] = 0.f;
    for (int g = 0; g < 8; ++g) {
        #pragma unroll
        for (int jj = 0; jj < 16; ++jj)
            s[jj] += part[(size_t)(g * 16 + jj) * HW + px];
    }
    float m = s[0];
    #pragma unroll
    for (int jj = 1; jj < 16; ++jj) m = fmaxf(m, s[jj]);
    float tot = 0.f;
    #pragma unroll
    for (int jj = 0; jj < 16; ++jj) { s[jj] = __expf(s[jj] - m); tot += s[jj]; }
    float inv = 1.f / tot;
    #pragma unroll
    for (int jj = 0; jj < 16; ++jj) sm[(size_t)jj * HW + px] = s[jj] * inv;
}

// ---------------- K4: xbar[c] = sum_j sm[j] * x[j][c] ---------------------
__global__ void k_xbar(const float* __restrict__ x, const float* __restrict__ sm,
                       float* __restrict__ xbar) {
    int c = blockIdx.x;
    int p = blockIdx.y * 1024 + threadIdx.x * 4;
    float4 acc = make_float4(0.f, 0.f, 0.f, 0.f);
    for (int jj = 0; jj < 16; ++jj) {
        float4 xv = *(const float4*)(x + (size_t)(jj * CDIM + c) * HW + p);
        float4 sv = *(const float4*)(sm + (size_t)jj * HW + p);
        acc.x += xv.x * sv.x; acc.y += xv.y * sv.y;
        acc.z += xv.z * sv.z; acc.w += xv.w * sv.w;
    }
    *(float4*)(xbar + (size_t)c * HW + p) = acc;
}

// ---------------- K5: out[i][c] = Wv*xbar + bv, broadcast over i ----------
// block: 256 thr = 16 px-quads x 16 c-groups(8). WvT staged in LDS (pad 132).
__global__ __launch_bounds__(256) void k_out(const float* __restrict__ xbar,
                                             const float* __restrict__ Wv,
                                             const float* __restrict__ bv,
                                             float* __restrict__ out) {
    __shared__ float wvt[128 * 132];
    const int tid = threadIdx.x;
    for (int idx = tid; idx < 128 * 128; idx += 256) {
        int c = idx >> 7, cp = idx & 127;
        wvt[cp * 132 + c] = Wv[idx];           // wvt[c'][c] = Wv[c][c']
    }
    __syncthreads();
    const int q   = tid & 15;
    const int cg  = tid >> 4;
    const int px0 = blockIdx.x * 64 + q * 4;
    const int c0  = cg * 8;
    float4 acc[8];
    #pragma unroll
    for (int k = 0; k < 8; ++k) acc[k] = make_float4(0.f, 0.f, 0.f, 0.f);
    for (int cp = 0; cp < 128; ++cp) {
        float4 xv = *(const float4*)(xbar + (size_t)cp * HW + px0);
        float4 wA = *(const float4*)(wvt + cp * 132 + c0);
        float4 wB = *(const float4*)(wvt + cp * 132 + c0 + 4);
        float wk[8] = {wA.x, wA.y, wA.z, wA.w, wB.x, wB.y, wB.z, wB.w};
        #pragma unroll
        for (int k = 0; k < 8; ++k) {
            acc[k].x += wk[k] * xv.x; acc[k].y += wk[k] * xv.y;
            acc[k].z += wk[k] * xv.z; acc[k].w += wk[k] * xv.w;
        }
    }
    #pragma unroll
    for (int k = 0; k < 8; ++k) {
        float b = bv[c0 + k];
        acc[k].x += b; acc[k].y += b; acc[k].z += b; acc[k].w += b;
    }
    for (int i = 0; i < 16; ++i) {
        #pragma unroll
        for (int k = 0; k < 8; ++k)
            *(float4*)(out + (size_t)((i * CDIM + c0 + k)) * HW + px0) = acc[k];
    }
}

extern "C" void kernel_launch(void* const* d_in, const int* in_sizes, int n_in,
                              void* d_out, int out_size, void* d_ws, size_t ws_size,
                              hipStream_t stream) {
    const float* x  = (const float*)d_in[0];
    const float* Wk = (const float*)d_in[3];
    const float* Wv = (const float*)d_in[5];
    const float* bv = (const float*)d_in[6];
    const float* Wa = (const float*)d_in[7];
    float* out = (float*)d_out;

    char* ws = (char*)d_ws;
    float* weff = (float*)(ws);                          // 12.8 KB (pad to 16 KB)
    float* part = (float*)(ws + 16384);                  // 8*16*9216*4 = 4.72 MB
    float* sm   = (float*)(ws + 16384 + 4718592);        // 16*9216*4  = 590 KB
    float* xbar = part;                                  // overlay: part dead after k3

    k_weff   <<<13,              256, 0, stream>>>(Wk, Wa, weff);
    k_conv   <<<dim3(16, 3, 8),  192, 0, stream>>>(x, weff, part);
    k_softmax<<<36,              256, 0, stream>>>(part, sm);
    k_xbar   <<<dim3(128, 9),    256, 0, stream>>>(x, sm, xbar);
    k_out    <<<144,             256, 0, stream>>>(xbar, Wv, bv, out);
}

// Round 2
// 155.284 us; speedup vs baseline: 1.0003x; 1.0003x over previous
//
#include <hip/hip_runtime.h>

// ConvAttention collapse:
//   softmax_j(Aq[i]+Ak[j]+ba) == softmax_j(Ak_linear[j])   (i-terms & biases cancel)
//   out[i] = Wv * (sum_j sm[j] * x[j]) + bv                (identical for all i)
// Only x, Wk, Wv, bv, Wa[:,C:] are used.

#define HW    9216      // 96*96
#define HDIM  96
#define WDIM  96
#define CDIM  128
#define LDIM  16

// ---------------- K1: effective conv weight -----------------------------
// weff[c'][tap] = sum_c Wk[c][c'] * Wa[(128+c)][tap]   (tap = kh*5+kw)
__global__ void k_weff(const float* __restrict__ Wk, const float* __restrict__ Wa,
                       float* __restrict__ weff) {
    int idx = blockIdx.x * 256 + threadIdx.x;
    if (idx >= 128 * 25) return;
    int cp = idx / 25, tap = idx % 25;
    float s = 0.f;
    for (int c = 0; c < 128; ++c)
        s += Wk[c * 128 + cp] * Wa[(128 + c) * 25 + tap];
    weff[idx] = s;
}

// ---------------- K2: fused 5x5 conv of x with weff ----------------------
// grid (16 imgs, 3 rowtiles of 32, 8 channel-groups of 16), block 192.
// Each block accumulates its 16 channels' contribution into part[g][j][:].
__global__ __launch_bounds__(192) void k_conv(const float* __restrict__ x,
                                              const float* __restrict__ weff,
                                              float* __restrict__ part) {
    const int j  = blockIdx.x;
    const int rt = blockIdx.y;
    const int g  = blockIdx.z;
    const int c0 = g * 16;
    __shared__ float tile[36 * 104];   // rows rowbase-2..+33, cols -4..99
    __shared__ float wsm[16 * 25];
    const int tid = threadIdx.x;
    for (int i = tid; i < 16 * 25; i += 192) wsm[i] = weff[c0 * 25 + i];
    const int cq = tid % 24;           // float4-column 0..23 (cols 4cq..4cq+3)
    const int rg = tid / 24;           // 0..7
    const int r0 = rg * 4;             // 4 output rows per thread
    const int rowbase = rt * 32;

    float4 acc[4];
    acc[0] = acc[1] = acc[2] = acc[3] = make_float4(0.f, 0.f, 0.f, 0.f);

    for (int ch = 0; ch < 16; ++ch) {
        const float* xc = x + (size_t)(j * CDIM + c0 + ch) * HW;
        __syncthreads();               // protect previous iter's tile reads
        for (int idx = tid; idx < 36 * 26; idx += 192) {
            int r = idx / 26, q = idx % 26;
            int gr = rowbase - 2 + r;
            int gc = q * 4 - 4;
            float4 v = make_float4(0.f, 0.f, 0.f, 0.f);
            if (gr >= 0 && gr < HDIM && gc >= 0 && gc < WDIM)
                v = *(const float4*)(xc + gr * WDIM + gc);
            *(float4*)(tile + r * 104 + q * 4) = v;
        }
        __syncthreads();
        const float* wc = wsm + ch * 25;
        for (int rr = 0; rr < 8; ++rr) {          // window tile rows r0..r0+7
            const float* trow = tile + (r0 + rr) * 104 + cq * 4;
            float4 a  = *(const float4*)(trow);
            float4 b  = *(const float4*)(trow + 4);
            float4 c4 = *(const float4*)(trow + 8);
            float win[12] = {a.x, a.y, a.z, a.w, b.x, b.y, b.z, b.w,
                             c4.x, c4.y, c4.z, c4.w};
            // win[i] is global col 4cq-4+i; output col 4cq+o needs i=o+kw+2
            #pragma unroll
            for (int orow = 0; orow < 4; ++orow) {
                int kh = rr - orow;
                if (kh < 0 || kh > 4) continue;   // wave-uniform branch
                #pragma unroll
                for (int kw = 0; kw < 5; ++kw) {
                    float w = wc[kh * 5 + kw];
                    acc[orow].x += w * win[kw + 2];
                    acc[orow].y += w * win[kw + 3];
                    acc[orow].z += w * win[kw + 4];
                    acc[orow].w += w * win[kw + 5];
                }
            }
        }
    }
    float* pr = part + (size_t)(g * 16 + j) * HW;
    #pragma unroll
    for (int orow = 0; orow < 4; ++orow) {
        int row = rowbase + r0 + orow;
        *(float4*)(pr + row * WDIM + cq * 4) = acc[orow];
    }
}

// ---------------- K3: combine partials + softmax over j ------------------
__global__ void k_softmax(const float* __restrict__ part, float* __restrict__ sm) {
    int px = blockIdx.x * 256 + threadIdx.x;   // 9216 total
    float s[16];
    #pragma unroll
    for (int jj = 0; jj < 16; ++jj) s[jj] = 0.f;
    for (int g = 0; g < 8; ++g) {
        #pragma unroll
        for (int jj = 0; jj < 16; ++jj)
            s[jj] += part[(size_t)(g * 16 + jj) * HW + px];
    }
    float m = s[0];
    #pragma unroll
    for (int jj = 1; jj < 16; ++jj) m = fmaxf(m, s[jj]);
    float tot = 0.f;
    #pragma unroll
    for (int jj = 0; jj < 16; ++jj) { s[jj] = __expf(s[jj] - m); tot += s[jj]; }
    float inv = 1.f / tot;
    #pragma unroll
    for (int jj = 0; jj < 16; ++jj) sm[(size_t)jj * HW + px] = s[jj] * inv;
}

// ---------------- K4: xbar[c] = sum_j sm[j] * x[j][c] ---------------------
__global__ void k_xbar(const float* __restrict__ x, const float* __restrict__ sm,
                       float* __restrict__ xbar) {
    int c = blockIdx.x;
    int p = blockIdx.y * 1024 + threadIdx.x * 4;
    float4 acc = make_float4(0.f, 0.f, 0.f, 0.f);
    for (int jj = 0; jj < 16; ++jj) {
        float4 xv = *(const float4*)(x + (size_t)(jj * CDIM + c) * HW + p);
        float4 sv = *(const float4*)(sm + (size_t)jj * HW + p);
        acc.x += xv.x * sv.x; acc.y += xv.y * sv.y;
        acc.z += xv.z * sv.z; acc.w += xv.w * sv.w;
    }
    *(float4*)(xbar + (size_t)c * HW + p) = acc;
}

// ---------------- K5: out[i][c] = Wv*xbar + bv, broadcast over i ----------
// block: 256 thr = 16 px-quads x 16 c-groups(8). WvT staged in LDS (pad 132).
__global__ __launch_bounds__(256) void k_out(const float* __restrict__ xbar,
                                             const float* __restrict__ Wv,
                                             const float* __restrict__ bv,
                                             float* __restrict__ out) {
    __shared__ float wvt[128 * 132];
    const int tid = threadIdx.x;
    for (int idx = tid; idx < 128 * 128; idx += 256) {
        int c = idx >> 7, cp = idx & 127;
        wvt[cp * 132 + c] = Wv[idx];           // wvt[c'][c] = Wv[c][c']
    }
    __syncthreads();
    const int q   = tid & 15;
    const int cg  = tid >> 4;
    const int px0 = blockIdx.x * 64 + q * 4;
    const int c0  = cg * 8;
    float4 acc[8];
    #pragma unroll
    for (int k = 0; k < 8; ++k) acc[k] = make_float4(0.f, 0.f, 0.f, 0.f);
    for (int cp = 0; cp < 128; ++cp) {
        float4 xv = *(const float4*)(xbar + (size_t)cp * HW + px0);
        float4 wA = *(const float4*)(wvt + cp * 132 + c0);
        float4 wB = *(const float4*)(wvt + cp * 132 + c0 + 4);
        float wk[8] = {wA.x, wA.y, wA.z, wA.w, wB.x, wB.y, wB.z, wB.w};
        #pragma unroll
        for (int k = 0; k < 8; ++k) {
            acc[k].x += wk[k] * xv.x; acc[k].y += wk[k] * xv.y;
            acc[k].z += wk[k] * xv.z; acc[k].w += wk[k] * xv.w;
        }
    }
    #pragma unroll
    for (int k = 0; k < 8; ++k) {
        float b = bv[c0 + k];
        acc[k].x += b; acc[k].y += b; acc[k].z += b; acc[k].w += b;
    }
    for (int i = 0; i < 16; ++i) {
        #pragma unroll
        for (int k = 0; k < 8; ++k)
            *(float4*)(out + (size_t)((i * CDIM + c0 + k)) * HW + px0) = acc[k];
    }
}

extern "C" void kernel_launch(void* const* d_in, const int* in_sizes, int n_in,
                              void* d_out, int out_size, void* d_ws, size_t ws_size,
                              hipStream_t stream) {
    const float* x  = (const float*)d_in[0];
    const float* Wk = (const float*)d_in[3];
    const float* Wv = (const float*)d_in[5];
    const float* bv = (const float*)d_in[6];
    const float* Wa = (const float*)d_in[7];
    float* out = (float*)d_out;

    char* ws = (char*)d_ws;
    float* weff = (float*)(ws);                          // 12.8 KB (pad to 16 KB)
    float* part = (float*)(ws + 16384);                  // 8*16*9216*4 = 4.72 MB
    float* sm   = (float*)(ws + 16384 + 4718592);        // 16*9216*4  = 590 KB
    float* xbar = part;                                  // overlay: part dead after k3

    k_weff   <<<13,              256, 0, stream>>>(Wk, Wa, weff);
    k_conv   <<<dim3(16, 3, 8),  192, 0, stream>>>(x, weff, part);
    k_softmax<<<36,              256, 0, stream>>>(part, sm);
    k_xbar   <<<dim3(128, 9),    256, 0, stream>>>(x, sm, xbar);
    k_out    <<<144,             256, 0, stream>>>(xbar, Wv, bv, out);
}

// Round 3
// 155.221 us; speedup vs baseline: 1.0007x; 1.0004x over previous
//
#include <hip/hip_runtime.h>

// ConvAttention collapse:
//   softmax_j(Aq[i]+Ak[j]+ba) == softmax_j(Ak_linear[j])   (i-terms & biases cancel)
//   out[i] = Wv * (sum_j sm[j] * x[j]) + bv                (identical for all i)
// Only x, Wk, Wv, bv, Wa[:,C:] are used.

#define HW    9216      // 96*96
#define HDIM  96
#define WDIM  96
#define CDIM  128
#define LDIM  16

// ---------------- K1: effective conv weight -----------------------------
// weff[c'][tap] = sum_c Wk[c][c'] * Wa[(128+c)][tap]   (tap = kh*5+kw)
__global__ void k_weff(const float* __restrict__ Wk, const float* __restrict__ Wa,
                       float* __restrict__ weff) {
    int idx = blockIdx.x * 256 + threadIdx.x;
    if (idx >= 128 * 25) return;
    int cp = idx / 25, tap = idx % 25;
    float s = 0.f;
    for (int c = 0; c < 128; ++c)
        s += Wk[c * 128 + cp] * Wa[(128 + c) * 25 + tap];
    weff[idx] = s;
}

// ---------------- K2: fused 5x5 conv of x with weff ----------------------
// grid (16 imgs, 3 rowtiles of 32, 8 channel-groups of 16), block 192.
// Each block accumulates its 16 channels' contribution into part[g][j][:].
__global__ __launch_bounds__(192) void k_conv(const float* __restrict__ x,
                                              const float* __restrict__ weff,
                                              float* __restrict__ part) {
    const int j  = blockIdx.x;
    const int rt = blockIdx.y;
    const int g  = blockIdx.z;
    const int c0 = g * 16;
    __shared__ float tile[36 * 104];   // rows rowbase-2..+33, cols -4..99
    __shared__ float wsm[16 * 25];
    const int tid = threadIdx.x;
    for (int i = tid; i < 16 * 25; i += 192) wsm[i] = weff[c0 * 25 + i];
    const int cq = tid % 24;           // float4-column 0..23 (cols 4cq..4cq+3)
    const int rg = tid / 24;           // 0..7
    const int r0 = rg * 4;             // 4 output rows per thread
    const int rowbase = rt * 32;

    float4 acc[4];
    acc[0] = acc[1] = acc[2] = acc[3] = make_float4(0.f, 0.f, 0.f, 0.f);

    for (int ch = 0; ch < 16; ++ch) {
        const float* xc = x + (size_t)(j * CDIM + c0 + ch) * HW;
        __syncthreads();               // protect previous iter's tile reads
        for (int idx = tid; idx < 36 * 26; idx += 192) {
            int r = idx / 26, q = idx % 26;
            int gr = rowbase - 2 + r;
            int gc = q * 4 - 4;
            float4 v = make_float4(0.f, 0.f, 0.f, 0.f);
            if (gr >= 0 && gr < HDIM && gc >= 0 && gc < WDIM)
                v = *(const float4*)(xc + gr * WDIM + gc);
            *(float4*)(tile + r * 104 + q * 4) = v;
        }
        __syncthreads();
        const float* wc = wsm + ch * 25;
        for (int rr = 0; rr < 8; ++rr) {          // window tile rows r0..r0+7
            const float* trow = tile + (r0 + rr) * 104 + cq * 4;
            float4 a  = *(const float4*)(trow);
            float4 b  = *(const float4*)(trow + 4);
            float4 c4 = *(const float4*)(trow + 8);
            float win[12] = {a.x, a.y, a.z, a.w, b.x, b.y, b.z, b.w,
                             c4.x, c4.y, c4.z, c4.w};
            // win[i] is global col 4cq-4+i; output col 4cq+o needs i=o+kw+2
            #pragma unroll
            for (int orow = 0; orow < 4; ++orow) {
                int kh = rr - orow;
                if (kh < 0 || kh > 4) continue;   // wave-uniform branch
                #pragma unroll
                for (int kw = 0; kw < 5; ++kw) {
                    float w = wc[kh * 5 + kw];
                    acc[orow].x += w * win[kw + 2];
                    acc[orow].y += w * win[kw + 3];
                    acc[orow].z += w * win[kw + 4];
                    acc[orow].w += w * win[kw + 5];
                }
            }
        }
    }
    float* pr = part + (size_t)(g * 16 + j) * HW;
    #pragma unroll
    for (int orow = 0; orow < 4; ++orow) {
        int row = rowbase + r0 + orow;
        *(float4*)(pr + row * WDIM + cq * 4) = acc[orow];
    }
}

// ---------------- K3: combine partials + softmax over j ------------------
__global__ void k_softmax(const float* __restrict__ part, float* __restrict__ sm) {
    int px = blockIdx.x * 256 + threadIdx.x;   // 9216 total
    float s[16];
    #pragma unroll
    for (int jj = 0; jj < 16; ++jj) s[jj] = 0.f;
    for (int g = 0; g < 8; ++g) {
        #pragma unroll
        for (int jj = 0; jj < 16; ++jj)
            s[jj] += part[(size_t)(g * 16 + jj) * HW + px];
    }
    float m = s[0];
    #pragma unroll
    for (int jj = 1; jj < 16; ++jj) m = fmaxf(m, s[jj]);
    float tot = 0.f;
    #pragma unroll
    for (int jj = 0; jj < 16; ++jj) { s[jj] = __expf(s[jj] - m); tot += s[jj]; }
    float inv = 1.f / tot;
    #pragma unroll
    for (int jj = 0; jj < 16; ++jj) sm[(size_t)jj * HW + px] = s[jj] * inv;
}

// ---------------- K4: xbar[c] = sum_j sm[j] * x[j][c] ---------------------
__global__ void k_xbar(const float* __restrict__ x, const float* __restrict__ sm,
                       float* __restrict__ xbar) {
    int c = blockIdx.x;
    int p = blockIdx.y * 1024 + threadIdx.x * 4;
    float4 acc = make_float4(0.f, 0.f, 0.f, 0.f);
    for (int jj = 0; jj < 16; ++jj) {
        float4 xv = *(const float4*)(x + (size_t)(jj * CDIM + c) * HW + p);
        float4 sv = *(const float4*)(sm + (size_t)jj * HW + p);
        acc.x += xv.x * sv.x; acc.y += xv.y * sv.y;
        acc.z += xv.z * sv.z; acc.w += xv.w * sv.w;
    }
    *(float4*)(xbar + (size_t)c * HW + p) = acc;
}

// ---------------- K5: out[i][c] = Wv*xbar + bv, broadcast over i ----------
// block: 256 thr = 16 px-quads x 16 c-groups(8). WvT staged in LDS (pad 132).
__global__ __launch_bounds__(256) void k_out(const float* __restrict__ xbar,
                                             const float* __restrict__ Wv,
                                             const float* __restrict__ bv,
                                             float* __restrict__ out) {
    __shared__ float wvt[128 * 132];
    const int tid = threadIdx.x;
    for (int idx = tid; idx < 128 * 128; idx += 256) {
        int c = idx >> 7, cp = idx & 127;
        wvt[cp * 132 + c] = Wv[idx];           // wvt[c'][c] = Wv[c][c']
    }
    __syncthreads();
    const int q   = tid & 15;
    const int cg  = tid >> 4;
    const int px0 = blockIdx.x * 64 + q * 4;
    const int c0  = cg * 8;
    float4 acc[8];
    #pragma unroll
    for (int k = 0; k < 8; ++k) acc[k] = make_float4(0.f, 0.f, 0.f, 0.f);
    for (int cp = 0; cp < 128; ++cp) {
        float4 xv = *(const float4*)(xbar + (size_t)cp * HW + px0);
        float4 wA = *(const float4*)(wvt + cp * 132 + c0);
        float4 wB = *(const float4*)(wvt + cp * 132 + c0 + 4);
        float wk[8] = {wA.x, wA.y, wA.z, wA.w, wB.x, wB.y, wB.z, wB.w};
        #pragma unroll
        for (int k = 0; k < 8; ++k) {
            acc[k].x += wk[k] * xv.x; acc[k].y += wk[k] * xv.y;
            acc[k].z += wk[k] * xv.z; acc[k].w += wk[k] * xv.w;
        }
    }
    #pragma unroll
    for (int k = 0; k < 8; ++k) {
        float b = bv[c0 + k];
        acc[k].x += b; acc[k].y += b; acc[k].z += b; acc[k].w += b;
    }
    for (int i = 0; i < 16; ++i) {
        #pragma unroll
        for (int k = 0; k < 8; ++k)
            *(float4*)(out + (size_t)((i * CDIM + c0 + k)) * HW + px0) = acc[k];
    }
}

extern "C" void kernel_launch(void* const* d_in, const int* in_sizes, int n_in,
                              void* d_out, int out_size, void* d_ws, size_t ws_size,
                              hipStream_t stream) {
    const float* x  = (const float*)d_in[0];
    const float* Wk = (const float*)d_in[3];
    const float* Wv = (const float*)d_in[5];
    const float* bv = (const float*)d_in[6];
    const float* Wa = (const float*)d_in[7];
    float* out = (float*)d_out;

    char* ws = (char*)d_ws;
    float* weff = (float*)(ws);                          // 12.8 KB (pad to 16 KB)
    float* part = (float*)(ws + 16384);                  // 8*16*9216*4 = 4.72 MB
    float* sm   = (float*)(ws + 16384 + 4718592);        // 16*9216*4  = 590 KB
    float* xbar = part;                                  // overlay: part dead after k3

    k_weff   <<<13,              256, 0, stream>>>(Wk, Wa, weff);
    k_conv   <<<dim3(16, 3, 8),  192, 0, stream>>>(x, weff, part);
    k_softmax<<<36,              256, 0, stream>>>(part, sm);
    k_xbar   <<<dim3(128, 9),    256, 0, stream>>>(x, sm, xbar);
    k_out    <<<144,             256, 0, stream>>>(xbar, Wv, bv, out);
}

// Round 4
// 155.191 us; speedup vs baseline: 1.0009x; 1.0002x over previous
//
#include <hip/hip_runtime.h>

// ConvAttention collapse:
//   softmax_j(Aq[i]+Ak[j]+ba) == softmax_j(Ak_linear[j])   (i-terms & biases cancel)
//   out[i] = Wv * (sum_j sm[j] * x[j]) + bv                (identical for all i)
// Only x, Wk, Wv, bv, Wa[:,C:] are used.

#define HW    9216      // 96*96
#define HDIM  96
#define WDIM  96
#define CDIM  128
#define LDIM  16

// ---------------- K1: effective conv weight -----------------------------
// weff[c'][tap] = sum_c Wk[c][c'] * Wa[(128+c)][tap]   (tap = kh*5+kw)
__global__ void k_weff(const float* __restrict__ Wk, const float* __restrict__ Wa,
                       float* __restrict__ weff) {
    int idx = blockIdx.x * 256 + threadIdx.x;
    if (idx >= 128 * 25) return;
    int cp = idx / 25, tap = idx % 25;
    float s = 0.f;
    for (int c = 0; c < 128; ++c)
        s += Wk[c * 128 + cp] * Wa[(128 + c) * 25 + tap];
    weff[idx] = s;
}

// ---------------- K2: fused 5x5 conv of x with weff ----------------------
// grid (16 imgs, 3 rowtiles of 32, 8 channel-groups of 16), block 192.
// Each block accumulates its 16 channels' contribution into part[g][j][:].
__global__ __launch_bounds__(192) void k_conv(const float* __restrict__ x,
                                              const float* __restrict__ weff,
                                              float* __restrict__ part) {
    const int j  = blockIdx.x;
    const int rt = blockIdx.y;
    const int g  = blockIdx.z;
    const int c0 = g * 16;
    __shared__ float tile[36 * 104];   // rows rowbase-2..+33, cols -4..99
    __shared__ float wsm[16 * 25];
    const int tid = threadIdx.x;
    for (int i = tid; i < 16 * 25; i += 192) wsm[i] = weff[c0 * 25 + i];
    const int cq = tid % 24;           // float4-column 0..23 (cols 4cq..4cq+3)
    const int rg = tid / 24;           // 0..7
    const int r0 = rg * 4;             // 4 output rows per thread
    const int rowbase = rt * 32;

    float4 acc[4];
    acc[0] = acc[1] = acc[2] = acc[3] = make_float4(0.f, 0.f, 0.f, 0.f);

    for (int ch = 0; ch < 16; ++ch) {
        const float* xc = x + (size_t)(j * CDIM + c0 + ch) * HW;
        __syncthreads();               // protect previous iter's tile reads
        for (int idx = tid; idx < 36 * 26; idx += 192) {
            int r = idx / 26, q = idx % 26;
            int gr = rowbase - 2 + r;
            int gc = q * 4 - 4;
            float4 v = make_float4(0.f, 0.f, 0.f, 0.f);
            if (gr >= 0 && gr < HDIM && gc >= 0 && gc < WDIM)
                v = *(const float4*)(xc + gr * WDIM + gc);
            *(float4*)(tile + r * 104 + q * 4) = v;
        }
        __syncthreads();
        const float* wc = wsm + ch * 25;
        for (int rr = 0; rr < 8; ++rr) {          // window tile rows r0..r0+7
            const float* trow = tile + (r0 + rr) * 104 + cq * 4;
            float4 a  = *(const float4*)(trow);
            float4 b  = *(const float4*)(trow + 4);
            float4 c4 = *(const float4*)(trow + 8);
            float win[12] = {a.x, a.y, a.z, a.w, b.x, b.y, b.z, b.w,
                             c4.x, c4.y, c4.z, c4.w};
            // win[i] is global col 4cq-4+i; output col 4cq+o needs i=o+kw+2
            #pragma unroll
            for (int orow = 0; orow < 4; ++orow) {
                int kh = rr - orow;
                if (kh < 0 || kh > 4) continue;   // wave-uniform branch
                #pragma unroll
                for (int kw = 0; kw < 5; ++kw) {
                    float w = wc[kh * 5 + kw];
                    acc[orow].x += w * win[kw + 2];
                    acc[orow].y += w * win[kw + 3];
                    acc[orow].z += w * win[kw + 4];
                    acc[orow].w += w * win[kw + 5];
                }
            }
        }
    }
    float* pr = part + (size_t)(g * 16 + j) * HW;
    #pragma unroll
    for (int orow = 0; orow < 4; ++orow) {
        int row = rowbase + r0 + orow;
        *(float4*)(pr + row * WDIM + cq * 4) = acc[orow];
    }
}

// ---------------- K3: combine partials + softmax over j ------------------
__global__ void k_softmax(const float* __restrict__ part, float* __restrict__ sm) {
    int px = blockIdx.x * 256 + threadIdx.x;   // 9216 total
    float s[16];
    #pragma unroll
    for (int jj = 0; jj < 16; ++jj) s[jj] = 0.f;
    for (int g = 0; g < 8; ++g) {
        #pragma unroll
        for (int jj = 0; jj < 16; ++jj)
            s[jj] += part[(size_t)(g * 16 + jj) * HW + px];
    }
    float m = s[0];
    #pragma unroll
    for (int jj = 1; jj < 16; ++jj) m = fmaxf(m, s[jj]);
    float tot = 0.f;
    #pragma unroll
    for (int jj = 0; jj < 16; ++jj) { s[jj] = __expf(s[jj] - m); tot += s[jj]; }
    float inv = 1.f / tot;
    #pragma unroll
    for (int jj = 0; jj < 16; ++jj) sm[(size_t)jj * HW + px] = s[jj] * inv;
}

// ---------------- K4: xbar[c] = sum_j sm[j] * x[j][c] ---------------------
__global__ void k_xbar(const float* __restrict__ x, const float* __restrict__ sm,
                       float* __restrict__ xbar) {
    int c = blockIdx.x;
    int p = blockIdx.y * 1024 + threadIdx.x * 4;
    float4 acc = make_float4(0.f, 0.f, 0.f, 0.f);
    for (int jj = 0; jj < 16; ++jj) {
        float4 xv = *(const float4*)(x + (size_t)(jj * CDIM + c) * HW + p);
        float4 sv = *(const float4*)(sm + (size_t)jj * HW + p);
        acc.x += xv.x * sv.x; acc.y += xv.y * sv.y;
        acc.z += xv.z * sv.z; acc.w += xv.w * sv.w;
    }
    *(float4*)(xbar + (size_t)c * HW + p) = acc;
}

// ---------------- K5: out[i][c] = Wv*xbar + bv, broadcast over i ----------
// block: 256 thr = 16 px-quads x 16 c-groups(8). WvT staged in LDS (pad 132).
__global__ __launch_bounds__(256) void k_out(const float* __restrict__ xbar,
                                             const float* __restrict__ Wv,
                                             const float* __restrict__ bv,
                                             float* __restrict__ out) {
    __shared__ float wvt[128 * 132];
    const int tid = threadIdx.x;
    for (int idx = tid; idx < 128 * 128; idx += 256) {
        int c = idx >> 7, cp = idx & 127;
        wvt[cp * 132 + c] = Wv[idx];           // wvt[c'][c] = Wv[c][c']
    }
    __syncthreads();
    const int q   = tid & 15;
    const int cg  = tid >> 4;
    const int px0 = blockIdx.x * 64 + q * 4;
    const int c0  = cg * 8;
    float4 acc[8];
    #pragma unroll
    for (int k = 0; k < 8; ++k) acc[k] = make_float4(0.f, 0.f, 0.f, 0.f);
    for (int cp = 0; cp < 128; ++cp) {
        float4 xv = *(const float4*)(xbar + (size_t)cp * HW + px0);
        float4 wA = *(const float4*)(wvt + cp * 132 + c0);
        float4 wB = *(const float4*)(wvt + cp * 132 + c0 + 4);
        float wk[8] = {wA.x, wA.y, wA.z, wA.w, wB.x, wB.y, wB.z, wB.w};
        #pragma unroll
        for (int k = 0; k < 8; ++k) {
            acc[k].x += wk[k] * xv.x; acc[k].y += wk[k] * xv.y;
            acc[k].z += wk[k] * xv.z; acc[k].w += wk[k] * xv.w;
        }
    }
    #pragma unroll
    for (int k = 0; k < 8; ++k) {
        float b = bv[c0 + k];
        acc[k].x += b; acc[k].y += b; acc[k].z += b; acc[k].w += b;
    }
    for (int i = 0; i < 16; ++i) {
        #pragma unroll
        for (int k = 0; k < 8; ++k)
            *(float4*)(out + (size_t)((i * CDIM + c0 + k)) * HW + px0) = acc[k];
    }
}

extern "C" void kernel_launch(void* const* d_in, const int* in_sizes, int n_in,
                              void* d_out, int out_size, void* d_ws, size_t ws_size,
                              hipStream_t stream) {
    const float* x  = (const float*)d_in[0];
    const float* Wk = (const float*)d_in[3];
    const float* Wv = (const float*)d_in[5];
    const float* bv = (const float*)d_in[6];
    const float* Wa = (const float*)d_in[7];
    float* out = (float*)d_out;

    char* ws = (char*)d_ws;
    float* weff = (float*)(ws);                          // 12.8 KB (pad to 16 KB)
    float* part = (float*)(ws + 16384);                  // 8*16*9216*4 = 4.72 MB
    float* sm   = (float*)(ws + 16384 + 4718592);        // 16*9216*4  = 590 KB
    float* xbar = part;                                  // overlay: part dead after k3

    k_weff   <<<13,              256, 0, stream>>>(Wk, Wa, weff);
    k_conv   <<<dim3(16, 3, 8),  192, 0, stream>>>(x, weff, part);
    k_softmax<<<36,              256, 0, stream>>>(part, sm);
    k_xbar   <<<dim3(128, 9),    256, 0, stream>>>(x, sm, xbar);
    k_out    <<<144,             256, 0, stream>>>(xbar, Wv, bv, out);
}